// Round 4
// baseline (275.719 us; speedup 1.0000x reference)
//
#include <hip/hip_runtime.h>

// Problem constants (from reference)
#define COLS    2048
#define CPC     32          // cells per column == 32 bits -> one word per column
#define NCELLS  65536       // COLS * CPC
#define SEGS    16
#define SYN     32
#define THRESH  13

#define CPW     8                      // cells per wave
#define CPB     (4 * CPW)              // 32 cells per block (4 waves)
#define PREDICT_GRID (NCELLS / CPB)    // 2048 blocks -> 8 blocks/CU, 32 waves/CU

// ---------------------------------------------------------------------------
// Kernel 1: active-cell phase (unchanged — correct, tiny, atomic-free).
// ---------------------------------------------------------------------------
__global__ __launch_bounds__(256) void tm_active_kernel(
    const float* __restrict__ active_columns,
    const float* __restrict__ prev_predictive,
    float* __restrict__ out_active,
    unsigned int* __restrict__ ws_mask,
    unsigned char* __restrict__ ws_flags)
{
    int n = blockIdx.x * 256 + threadIdx.x;   // cell index, grid is exact
    int c = n >> 5;                            // column
    int j = n & 31;                            // cell within column
    int lane = threadIdx.x & 63;

    bool predbit    = prev_predictive[n] > 0.0f;
    bool col_active = active_columns[c] > 0.0f;

    unsigned long long pb = __ballot(predbit);
    unsigned int colmask = (lane < 32) ? (unsigned int)pb : (unsigned int)(pb >> 32);
    bool has_pred = (colmask != 0u);

    bool active = col_active && (has_pred ? predbit : true);
    out_active[n] = active ? 1.0f : 0.0f;

    unsigned long long ab = __ballot(active);
    if (lane == 0)  ws_mask[c] = (unsigned int)ab;
    if (lane == 32) ws_mask[c] = (unsigned int)(ab >> 32);

    if (j == 0)
        ws_flags[c] = (unsigned char)((col_active ? 1 : 0) |
                                      ((col_active && has_pred) ? 2 : 0));
}

// ---------------------------------------------------------------------------
// Kernel 2: predictive phase — max-occupancy VGPR streaming.
//
// R8 theory: R7's VGPR_Count=52 proves the compiler could NOT keep the
// 32-VGPR pair prefetch live (needs ~70) — loads sank into the consume
// phase, so effective per-wave outstanding was ~200 B, not 8 KB; delivered
// BW stuck at ~13 GB/s/CU across 5 structures while write-only fills hit
// 7 TB/s (2x our read rate). Fix: cell-granular double buffer (16+16 VGPR)
// that FITS the 64-VGPR occupancy bin, __launch_bounds__(256,8) to force
// that bin, and 8 blocks/CU (grid 2048, LDS 8 KB) -> 32 waves/CU each with
// a genuinely-live 4 KB prefetch. perm = nontemporal (R6 +22%), issued
// before the L3-resident pre loads (longest latency first).
// ---------------------------------------------------------------------------
typedef int   i4 __attribute__((ext_vector_type(4)));
typedef float f4 __attribute__((ext_vector_type(4)));

__device__ __forceinline__ int cell_count(const unsigned int* mask,
                                          i4 p0, i4 p1, f4 q0, f4 q1)
{
    int c0 = 0, c1 = 0;
    c0 += (q0.x >= 0.5f && ((mask[(unsigned)p0.x >> 5] >> ((unsigned)p0.x & 31u)) & 1u)) ? 1 : 0;
    c0 += (q0.y >= 0.5f && ((mask[(unsigned)p0.y >> 5] >> ((unsigned)p0.y & 31u)) & 1u)) ? 1 : 0;
    c0 += (q0.z >= 0.5f && ((mask[(unsigned)p0.z >> 5] >> ((unsigned)p0.z & 31u)) & 1u)) ? 1 : 0;
    c0 += (q0.w >= 0.5f && ((mask[(unsigned)p0.w >> 5] >> ((unsigned)p0.w & 31u)) & 1u)) ? 1 : 0;
    c1 += (q1.x >= 0.5f && ((mask[(unsigned)p1.x >> 5] >> ((unsigned)p1.x & 31u)) & 1u)) ? 1 : 0;
    c1 += (q1.y >= 0.5f && ((mask[(unsigned)p1.y >> 5] >> ((unsigned)p1.y & 31u)) & 1u)) ? 1 : 0;
    c1 += (q1.z >= 0.5f && ((mask[(unsigned)p1.z >> 5] >> ((unsigned)p1.z & 31u)) & 1u)) ? 1 : 0;
    c1 += (q1.w >= 0.5f && ((mask[(unsigned)p1.w >> 5] >> ((unsigned)p1.w & 31u)) & 1u)) ? 1 : 0;

    // lane holds int4 elems lane and lane+64 of the cell's 128; int4 idx e ->
    // segment e/8. Butterfly-ADD over the 8-lane group gives full segment
    // counts (seg g in lo 16 bits, seg g+8 in hi), then unpack+max and
    // butterfly-MAX across the 8 groups -> max over all 16 segments.
    int v = c0 | (c1 << 16);
    v += __shfl_xor(v, 1, 64);
    v += __shfl_xor(v, 2, 64);
    v += __shfl_xor(v, 4, 64);
    int m = max(v & 0xffff, v >> 16);
    m = max(m, __shfl_xor(m, 8, 64));
    m = max(m, __shfl_xor(m, 16, 64));
    m = max(m, __shfl_xor(m, 32, 64));
    return m;
}

// Load one cell into 4 named vec4 regs (16 VGPR). perm (nt, HBM-latency)
// issued first, pre (L3-hit) second. Cell stride = 128 vec4 (2048 B).
#define LOADCELL(P0,P1,Q0,Q1, cell) do {                                     \
    const f4* _q = gq + (cell) * 128;                                        \
    const i4* _p = gp + (cell) * 128;                                        \
    Q0 = __builtin_nontemporal_load(_q);                                     \
    Q1 = __builtin_nontemporal_load(_q + 64);                                \
    P0 = _p[0];                                                              \
    P1 = _p[64];                                                             \
} while (0)

__global__ __launch_bounds__(256, 8) void tm_predict_kernel(
    const int*   __restrict__ seg_pre,
    const float* __restrict__ seg_perm,
    const unsigned int* __restrict__ ws_mask,
    const unsigned char* __restrict__ ws_flags,
    float* __restrict__ out_pred,
    float* __restrict__ out_anomaly)
{
    __shared__ unsigned int mask[COLS];       // 8 KB active bitmask (only LDS)

    int tid  = threadIdx.x;
    int wave = tid >> 6;
    int lane = tid & 63;
    int base = blockIdx.x * CPB + wave * CPW; // first cell of this wave

    const i4* gp = (const i4*)(seg_pre  + (size_t)base * 512) + lane;
    const f4* gq = (const f4*)(seg_perm + (size_t)base * 512) + lane;

    // Cell register buffers A/B (16 VGPR each), static names only (rule #20).
    i4 pA0, pA1, pB0, pB1;
    f4 qA0, qA1, qB0, qB1;

    // ---- Prologue: issue cell 0 loads, stage mask, barrier ----
    LOADCELL(pA0,pA1,qA0,qA1, 0);

    ((uint4*)mask)[tid]       = ((const uint4*)ws_mask)[tid];
    ((uint4*)mask)[tid + 256] = ((const uint4*)ws_mask)[tid + 256];

    __syncthreads();   // mask visible to all waves

    // ---- Main loop: 8 cells, ping-pong A/B, loads lead consumes by 1 cell ----
    unsigned pmask = 0;
    #pragma unroll
    for (int j = 0; j < CPW; j += 2) {
        LOADCELL(pB0,pB1,qB0,qB1, j + 1);

        int m0 = cell_count(mask, pA0, pA1, qA0, qA1);
        pmask |= (m0 >= THRESH) ? (1u << j) : 0u;

        if (j + 2 < CPW)
            LOADCELL(pA0,pA1,qA0,qA1, j + 2);

        int m1 = cell_count(mask, pB0, pB1, qB0, qB1);
        pmask |= (m1 >= THRESH) ? (1u << (j + 1)) : 0u;
    }

    // ---- Single coalesced result store per wave ----
    if (lane < CPW)
        out_pred[base + lane] = ((pmask >> lane) & 1u) ? 1.0f : 0.0f;

    // ---- Anomaly: block 0 / wave 0 reduces 2048 flag bytes (no LDS) ----
    if (blockIdx.x == 0 && tid < 64) {
        const unsigned int* f = (const unsigned int*)ws_flags;
        int na = 0, np = 0;
        #pragma unroll
        for (int i = 0; i < 8; ++i) {
            unsigned w = f[tid * 8 + i];
            na += __popc(w & 0x01010101u);
            np += __popc(w & 0x02020202u);
        }
        int v = na | (np << 16);
        v += __shfl_xor(v, 1, 64);
        v += __shfl_xor(v, 2, 64);
        v += __shfl_xor(v, 4, 64);
        v += __shfl_xor(v, 8, 64);
        v += __shfl_xor(v, 16, 64);
        v += __shfl_xor(v, 32, 64);
        if (tid == 0) {
            int NA = v & 0xffff, NP = v >> 16;
            *out_anomaly = 1.0f - (float)NP / (float)(NA > 1 ? NA : 1);
        }
    }
}

// ---------------------------------------------------------------------------
// Inputs (setup_inputs order):
//   d_in[0] active_columns  f32 [2048]
//   d_in[1] prev_active     f32 [65536]   (unused by the reference)
//   d_in[2] prev_predictive f32 [65536]
//   d_in[3] seg_pre         i32 [65536*16*32]
//   d_in[4] seg_perm        f32 [65536*16*32]
// Output: f32 [65536 active | 65536 predictive | 1 anomaly]
// Workspace: ws[0..2047] u32 bitmask, then 2048 u8 column flags
// ---------------------------------------------------------------------------
extern "C" void kernel_launch(void* const* d_in, const int* in_sizes, int n_in,
                              void* d_out, int out_size, void* d_ws, size_t ws_size,
                              hipStream_t stream) {
    const float* active_columns  = (const float*)d_in[0];
    const float* prev_predictive = (const float*)d_in[2];
    const int*   seg_pre         = (const int*)d_in[3];
    const float* seg_perm        = (const float*)d_in[4];
    float* out = (float*)d_out;

    unsigned int*  ws_mask  = (unsigned int*)d_ws;
    unsigned char* ws_flags = (unsigned char*)d_ws + COLS * sizeof(unsigned int);

    tm_active_kernel<<<NCELLS / 256, 256, 0, stream>>>(
        active_columns, prev_predictive, out, ws_mask, ws_flags);

    tm_predict_kernel<<<PREDICT_GRID, 256, 0, stream>>>(
        seg_pre, seg_perm, ws_mask, ws_flags,
        out + NCELLS, out + 2 * NCELLS);
}

// Round 5
// 275.205 us; speedup vs baseline: 1.0019x; 1.0019x over previous
//
#include <hip/hip_runtime.h>

// Problem constants (from reference)
#define COLS    2048
#define CPC     32          // cells per column == 32 bits -> one word per column
#define NCELLS  65536       // COLS * CPC
#define SEGS    16
#define SYN     32
#define THRESH  13

#define CPW     8                      // cells per wave
#define CPB     (4 * CPW)              // 32 cells per block (4 waves)
#define PREDICT_GRID (NCELLS / CPB)    // 2048 blocks -> 8 blocks/CU, 32 waves/CU

// ---------------------------------------------------------------------------
// Kernel 1: active-cell phase (unchanged — correct, tiny, atomic-free).
// ---------------------------------------------------------------------------
__global__ __launch_bounds__(256) void tm_active_kernel(
    const float* __restrict__ active_columns,
    const float* __restrict__ prev_predictive,
    float* __restrict__ out_active,
    unsigned int* __restrict__ ws_mask,
    unsigned char* __restrict__ ws_flags)
{
    int n = blockIdx.x * 256 + threadIdx.x;   // cell index, grid is exact
    int c = n >> 5;                            // column
    int j = n & 31;                            // cell within column
    int lane = threadIdx.x & 63;

    bool predbit    = prev_predictive[n] > 0.0f;
    bool col_active = active_columns[c] > 0.0f;

    unsigned long long pb = __ballot(predbit);
    unsigned int colmask = (lane < 32) ? (unsigned int)pb : (unsigned int)(pb >> 32);
    bool has_pred = (colmask != 0u);

    bool active = col_active && (has_pred ? predbit : true);
    out_active[n] = active ? 1.0f : 0.0f;

    unsigned long long ab = __ballot(active);
    if (lane == 0)  ws_mask[c] = (unsigned int)ab;
    if (lane == 32) ws_mask[c] = (unsigned int)(ab >> 32);

    if (j == 0)
        ws_flags[c] = (unsigned char)((col_active ? 1 : 0) |
                                      ((col_active && has_pred) ? 2 : 0));
}

// ---------------------------------------------------------------------------
// Kernel 2: predictive phase — VGPR streaming with ENFORCED double-buffer.
//
// R9: R3's VGPR_Count=52 proved the scheduler sinks prefetch loads into the
// consume phase (serializing: load A; use A; load B; use B -> ~200 B/wave in
// flight, not 4 KB). R4 fixed the occupancy bin but not the sinking. This
// round pins the pipeline with sched_barrier(0) after each load cluster:
// loads can no longer move below the next consume, so the waitcnt pass must
// emit s_waitcnt vmcnt(4) and each wave genuinely holds 4 KB in flight
// (x 32 waves/CU = 128 KB/CU). Single-variable change vs R4.
// perm = nontemporal (R6 +22%), issued before the L3-resident pre loads.
// ---------------------------------------------------------------------------
typedef int   i4 __attribute__((ext_vector_type(4)));
typedef float f4 __attribute__((ext_vector_type(4)));

__device__ __forceinline__ int cell_count(const unsigned int* mask,
                                          i4 p0, i4 p1, f4 q0, f4 q1)
{
    int c0 = 0, c1 = 0;
    c0 += (q0.x >= 0.5f && ((mask[(unsigned)p0.x >> 5] >> ((unsigned)p0.x & 31u)) & 1u)) ? 1 : 0;
    c0 += (q0.y >= 0.5f && ((mask[(unsigned)p0.y >> 5] >> ((unsigned)p0.y & 31u)) & 1u)) ? 1 : 0;
    c0 += (q0.z >= 0.5f && ((mask[(unsigned)p0.z >> 5] >> ((unsigned)p0.z & 31u)) & 1u)) ? 1 : 0;
    c0 += (q0.w >= 0.5f && ((mask[(unsigned)p0.w >> 5] >> ((unsigned)p0.w & 31u)) & 1u)) ? 1 : 0;
    c1 += (q1.x >= 0.5f && ((mask[(unsigned)p1.x >> 5] >> ((unsigned)p1.x & 31u)) & 1u)) ? 1 : 0;
    c1 += (q1.y >= 0.5f && ((mask[(unsigned)p1.y >> 5] >> ((unsigned)p1.y & 31u)) & 1u)) ? 1 : 0;
    c1 += (q1.z >= 0.5f && ((mask[(unsigned)p1.z >> 5] >> ((unsigned)p1.z & 31u)) & 1u)) ? 1 : 0;
    c1 += (q1.w >= 0.5f && ((mask[(unsigned)p1.w >> 5] >> ((unsigned)p1.w & 31u)) & 1u)) ? 1 : 0;

    // lane holds int4 elems lane and lane+64 of the cell's 128; int4 idx e ->
    // segment e/8. Butterfly-ADD over the 8-lane group gives full segment
    // counts (seg g in lo 16 bits, seg g+8 in hi), then unpack+max and
    // butterfly-MAX across the 8 groups -> max over all 16 segments.
    int v = c0 | (c1 << 16);
    v += __shfl_xor(v, 1, 64);
    v += __shfl_xor(v, 2, 64);
    v += __shfl_xor(v, 4, 64);
    int m = max(v & 0xffff, v >> 16);
    m = max(m, __shfl_xor(m, 8, 64));
    m = max(m, __shfl_xor(m, 16, 64));
    m = max(m, __shfl_xor(m, 32, 64));
    return m;
}

// Load one cell into 4 named vec4 regs (16 VGPR). perm (nt, HBM-latency)
// issued first, pre (L3-hit) second. Cell stride = 128 vec4 (2048 B).
#define LOADCELL(P0,P1,Q0,Q1, cell) do {                                     \
    const f4* _q = gq + (cell) * 128;                                        \
    const i4* _p = gp + (cell) * 128;                                        \
    Q0 = __builtin_nontemporal_load(_q);                                     \
    Q1 = __builtin_nontemporal_load(_q + 64);                                \
    P0 = _p[0];                                                              \
    P1 = _p[64];                                                             \
} while (0)

// Scheduler fence: nothing may cross (pins load clusters above consumes).
#define SCHED_FENCE() __builtin_amdgcn_sched_barrier(0)

__global__ __launch_bounds__(256, 8) void tm_predict_kernel(
    const int*   __restrict__ seg_pre,
    const float* __restrict__ seg_perm,
    const unsigned int* __restrict__ ws_mask,
    const unsigned char* __restrict__ ws_flags,
    float* __restrict__ out_pred,
    float* __restrict__ out_anomaly)
{
    __shared__ unsigned int mask[COLS];       // 8 KB active bitmask (only LDS)

    int tid  = threadIdx.x;
    int wave = tid >> 6;
    int lane = tid & 63;
    int base = blockIdx.x * CPB + wave * CPW; // first cell of this wave

    const i4* gp = (const i4*)(seg_pre  + (size_t)base * 512) + lane;
    const f4* gq = (const f4*)(seg_perm + (size_t)base * 512) + lane;

    // Cell register buffers A/B (16 VGPR each), static names only (rule #20).
    i4 pA0, pA1, pB0, pB1;
    f4 qA0, qA1, qB0, qB1;

    // ---- Prologue: issue cell 0 loads, stage mask, barrier ----
    LOADCELL(pA0,pA1,qA0,qA1, 0);
    SCHED_FENCE();

    ((uint4*)mask)[tid]       = ((const uint4*)ws_mask)[tid];
    ((uint4*)mask)[tid + 256] = ((const uint4*)ws_mask)[tid + 256];

    __syncthreads();   // mask visible to all waves

    // ---- Main loop: 8 cells, ping-pong A/B, pipeline ENFORCED by fences ----
    unsigned pmask = 0;
    #pragma unroll
    for (int j = 0; j < CPW; j += 2) {
        LOADCELL(pB0,pB1,qB0,qB1, j + 1);
        SCHED_FENCE();                       // B's loads stay above consume(A)

        int m0 = cell_count(mask, pA0, pA1, qA0, qA1);
        pmask |= (m0 >= THRESH) ? (1u << j) : 0u;

        if (j + 2 < CPW) {
            LOADCELL(pA0,pA1,qA0,qA1, j + 2);
        }
        SCHED_FENCE();                       // A's loads stay above consume(B)

        int m1 = cell_count(mask, pB0, pB1, qB0, qB1);
        pmask |= (m1 >= THRESH) ? (1u << (j + 1)) : 0u;
    }

    // ---- Single coalesced result store per wave ----
    if (lane < CPW)
        out_pred[base + lane] = ((pmask >> lane) & 1u) ? 1.0f : 0.0f;

    // ---- Anomaly: block 0 / wave 0 reduces 2048 flag bytes (no LDS) ----
    if (blockIdx.x == 0 && tid < 64) {
        const unsigned int* f = (const unsigned int*)ws_flags;
        int na = 0, np = 0;
        #pragma unroll
        for (int i = 0; i < 8; ++i) {
            unsigned w = f[tid * 8 + i];
            na += __popc(w & 0x01010101u);
            np += __popc(w & 0x02020202u);
        }
        int v = na | (np << 16);
        v += __shfl_xor(v, 1, 64);
        v += __shfl_xor(v, 2, 64);
        v += __shfl_xor(v, 4, 64);
        v += __shfl_xor(v, 8, 64);
        v += __shfl_xor(v, 16, 64);
        v += __shfl_xor(v, 32, 64);
        if (tid == 0) {
            int NA = v & 0xffff, NP = v >> 16;
            *out_anomaly = 1.0f - (float)NP / (float)(NA > 1 ? NA : 1);
        }
    }
}

// ---------------------------------------------------------------------------
// Inputs (setup_inputs order):
//   d_in[0] active_columns  f32 [2048]
//   d_in[1] prev_active     f32 [65536]   (unused by the reference)
//   d_in[2] prev_predictive f32 [65536]
//   d_in[3] seg_pre         i32 [65536*16*32]
//   d_in[4] seg_perm        f32 [65536*16*32]
// Output: f32 [65536 active | 65536 predictive | 1 anomaly]
// Workspace: ws[0..2047] u32 bitmask, then 2048 u8 column flags
// ---------------------------------------------------------------------------
extern "C" void kernel_launch(void* const* d_in, const int* in_sizes, int n_in,
                              void* d_out, int out_size, void* d_ws, size_t ws_size,
                              hipStream_t stream) {
    const float* active_columns  = (const float*)d_in[0];
    const float* prev_predictive = (const float*)d_in[2];
    const int*   seg_pre         = (const int*)d_in[3];
    const float* seg_perm        = (const float*)d_in[4];
    float* out = (float*)d_out;

    unsigned int*  ws_mask  = (unsigned int*)d_ws;
    unsigned char* ws_flags = (unsigned char*)d_ws + COLS * sizeof(unsigned int);

    tm_active_kernel<<<NCELLS / 256, 256, 0, stream>>>(
        active_columns, prev_predictive, out, ws_mask, ws_flags);

    tm_predict_kernel<<<PREDICT_GRID, 256, 0, stream>>>(
        seg_pre, seg_perm, ws_mask, ws_flags,
        out + NCELLS, out + 2 * NCELLS);
}